// Round 1
// baseline (186.360 us; speedup 1.0000x reference)
//
#include <hip/hip_runtime.h>

#define NP 15
#define NK 17
#define HH 256
#define WW 256
#define RAD2 9   // RADIUS^2

// ---------------- Kernel A: sum of softplus over all pred elements ----------
__global__ __launch_bounds__(256) void softplus_sum_kernel(
    const float4* __restrict__ x, int n4, double* __restrict__ ws_sum) {
    float acc = 0.f;
    int idx = blockIdx.x * blockDim.x + threadIdx.x;
    int stride = gridDim.x * blockDim.x;
    for (int i = idx; i < n4; i += stride) {
        float4 v = x[i];
        // softplus(x) = max(x,0) + log(1 + exp(-|x|))  (numerically stable)
        acc += fmaxf(v.x, 0.f) + __logf(1.f + __expf(-fabsf(v.x)));
        acc += fmaxf(v.y, 0.f) + __logf(1.f + __expf(-fabsf(v.y)));
        acc += fmaxf(v.z, 0.f) + __logf(1.f + __expf(-fabsf(v.z)));
        acc += fmaxf(v.w, 0.f) + __logf(1.f + __expf(-fabsf(v.w)));
    }
    // wave64 reduce
    #pragma unroll
    for (int off = 32; off > 0; off >>= 1)
        acc += __shfl_down(acc, off, 64);
    __shared__ float wsums[4];  // 256 threads = 4 waves
    int lane = threadIdx.x & 63;
    int wave = threadIdx.x >> 6;
    if (lane == 0) wsums[wave] = acc;
    __syncthreads();
    if (threadIdx.x == 0) {
        float s = wsums[0] + wsums[1] + wsums[2] + wsums[3];
        atomicAdd(ws_sum, (double)s);  // device-scope f64 atomic
    }
}

// -------- Kernel B: weighted keypoint disk sums + final combine -------------
// One block of 256 threads; thread t handles keypoint t (t < NP*NK).
__global__ __launch_bounds__(256) void keypoint_finish_kernel(
    const float* __restrict__ pred, const float* __restrict__ kp,
    const double* __restrict__ ws_sum, float* __restrict__ out) {
    int t = threadIdx.x;
    float wsum = 0.f;
    if (t < NP * NK) {
        int p = t / NK;
        float xf = kp[2 * t];
        float yf = kp[2 * t + 1];
        bool valid = ((xf != 0.f) && (xf != -1.f)) || ((yf != 0.f) && (yf != -1.f));
        if (valid) {
            int xi = (int)xf;  // truncation, matches astype(int32)
            int yi = (int)yf;
            const float* base = pred + (size_t)t * (HH * WW);
            float s = 0.f;
            #pragma unroll
            for (int dy = -3; dy <= 3; ++dy) {
                int y = yi + dy;
                if (y < 0 || y >= HH) continue;
                #pragma unroll
                for (int dx = -3; dx <= 3; ++dx) {
                    if (dy * dy + dx * dx > RAD2) continue;
                    int xx = xi + dx;
                    if (xx < 0 || xx >= WW) continue;
                    s += base[y * WW + xx];
                }
            }
            wsum = (float)(NP - p) * s;
        }
    }
    // block reduce (wave shuffle + LDS)
    #pragma unroll
    for (int off = 32; off > 0; off >>= 1)
        wsum += __shfl_down(wsum, off, 64);
    __shared__ float wsums[4];
    int lane = t & 63;
    int wave = t >> 6;
    if (lane == 0) wsums[wave] = wsum;
    __syncthreads();
    if (t == 0) {
        double total_w = (double)(wsums[0] + wsums[1] + wsums[2] + wsums[3]);
        const double N = (double)NP * NK * HH * WW;
        double softplus_mean = ws_sum[0] / N;
        double heatmap_loss = softplus_mean - total_w / ((double)NP * N);
        out[0] = (float)(4.0 * heatmap_loss + 0.02);
    }
}

extern "C" void kernel_launch(void* const* d_in, const int* in_sizes, int n_in,
                              void* d_out, int out_size, void* d_ws, size_t ws_size,
                              hipStream_t stream) {
    const float* pred = (const float*)d_in[0];      // [15,17,256,256] fp32
    const float* kp   = (const float*)d_in[2];      // [15,17,2] fp32
    float* out = (float*)d_out;
    double* ws_sum = (double*)d_ws;

    // ws is poisoned to 0xAA every call — zero the accumulator.
    hipMemsetAsync(ws_sum, 0, sizeof(double), stream);

    const int n = NP * NK * HH * WW;   // 16,711,680 (divisible by 4)
    const int n4 = n / 4;
    int blocks = 4096;                 // 16 blocks/CU, ~4 float4 per thread
    softplus_sum_kernel<<<blocks, 256, 0, stream>>>(
        (const float4*)pred, n4, ws_sum);
    keypoint_finish_kernel<<<1, 256, 0, stream>>>(pred, kp, ws_sum, out);
}